// Round 4
// baseline (237.073 us; speedup 1.0000x reference)
//
#include <hip/hip_runtime.h>

// CausalSelfAttention: B=8, S=2048, D=512, fp32 in/out, Q=K=V=x, no scale.
// Round 4: phase-offset staging pipeline.
//   Same fragment-packed layout + partition as round 3 (verified), but the
//   K/V staging for tile kt+1 is issued one phase EARLY so the barrier that
//   drains it sits a full compute phase later:
//     QK(K[kt]) | B1 | stage K[kt+1]; softmax; PV(V[kt]) | B2 | stage V[kt+1]
//   Single 32KB K + 32KB V buffers stay correct: each buffer's readers finish
//   before the barrier that precedes its restage. Exposed vmcnt drain ~0.
//   Block pairing: j=bid>>3, t = (j&1) ? j>>1 : 63-(j>>1) -> adjacent bids are
//   (heavy, light) complements summing to 65 tiles (robust on sequential fill).
//   Pack: grid-stride 512 blocks x 4 tiles, register-prefetch of next tile
//   issued before the emit phase (global-load latency overlaps emit+barriers).
// ws: [0,16MiB) Kf, [16MiB,32MiB) Vf.
//   Kf[b][kg:128][db:16][lane:64][8]  elem = x[b][16*kg+l15][32*db+8*quad+j]
//   Vf[b][dg:32][kb:64][lane:64][8]   elem = x[b][32*kb+8*quad+j][16*dg+l15]

#define S_LEN 2048
#define D_DIM 512
#define BATCH_ELEMS 1048576  // 2 MiB bf16 per batch per array

typedef short s16x8 __attribute__((ext_vector_type(8)));
typedef float f32x4 __attribute__((ext_vector_type(4)));

__device__ __forceinline__ unsigned short f2b_rne(float f) {
  unsigned int u = __float_as_uint(f);
  return (unsigned short)((u + 0x7FFFu + ((u >> 16) & 1u)) >> 16);
}
__device__ __forceinline__ unsigned short f2b_fast(float f) {
  return (unsigned short)((__float_as_uint(f) + 0x8000u) >> 16);
}

template <int CTRL>
__device__ __forceinline__ float dppf(float x) {
  return __uint_as_float((unsigned)__builtin_amdgcn_update_dpp(
      0, (int)__float_as_uint(x), CTRL, 0xF, 0xF, true));
}
__device__ __forceinline__ float red16_max(float v) {
  v = fmaxf(v, dppf<0xB1>(v));   // xor 1
  v = fmaxf(v, dppf<0x4E>(v));   // xor 2
  v = fmaxf(v, dppf<0x124>(v));  // row_ror:4
  v = fmaxf(v, dppf<0x128>(v));  // row_ror:8
  return v;
}
__device__ __forceinline__ float red16_sum(float v) {
  v += dppf<0xB1>(v);
  v += dppf<0x4E>(v);
  v += dppf<0x124>(v);
  v += dppf<0x128>(v);
  return v;
}

// ---------------------------------------------------------------------------
// Pack: grid-stride over 4 tiles/block, register prefetch of the next tile.
// Per tile: 64x64 block of x. A=[s][d] bf16, T=[d][s] bf16 (stride 72).
// ---------------------------------------------------------------------------
__global__ __launch_bounds__(256)
void pack_kernel(const float* __restrict__ x,
                 unsigned short* __restrict__ Kf,
                 unsigned short* __restrict__ Vf) {
  __shared__ unsigned short A[64 * 72];
  __shared__ unsigned short T[64 * 72];
  const int tid = threadIdx.x;
  const int row = tid >> 3, c = tid & 7;          // pass-1 coords (x2 rows)
  float4 r0a, r0b, r1a, r1b;                       // prefetch regs (2 slots x 32B)

  // prefetch tile 0
  {
    int tix = blockIdx.x;
    int b = tix >> 8, rem = tix & 255;
    int s0 = (rem >> 3) * 64, d0 = (rem & 7) * 64;
    const float* src0 = x + ((size_t)(b * S_LEN + s0 + row)) * D_DIM + d0 + c * 8;
    const float* src1 = x + ((size_t)(b * S_LEN + s0 + 32 + row)) * D_DIM + d0 + c * 8;
    r0a = *(const float4*)(src0); r0b = *(const float4*)(src0 + 4);
    r1a = *(const float4*)(src1); r1b = *(const float4*)(src1 + 4);
  }

  for (int i = 0; i < 4; ++i) {
    const int tix = blockIdx.x + 512 * i;
    const int b = tix >> 8, rem = tix & 255;
    const int s0 = (rem >> 3) * 64, d0 = (rem & 7) * 64;

    // convert prefetched regs -> A
    {
      s16x8 o;
      o[0] = (short)f2b_rne(r0a.x); o[1] = (short)f2b_rne(r0a.y);
      o[2] = (short)f2b_rne(r0a.z); o[3] = (short)f2b_rne(r0a.w);
      o[4] = (short)f2b_rne(r0b.x); o[5] = (short)f2b_rne(r0b.y);
      o[6] = (short)f2b_rne(r0b.z); o[7] = (short)f2b_rne(r0b.w);
      *(s16x8*)&A[row * 72 + c * 8] = o;
      o[0] = (short)f2b_rne(r1a.x); o[1] = (short)f2b_rne(r1a.y);
      o[2] = (short)f2b_rne(r1a.z); o[3] = (short)f2b_rne(r1a.w);
      o[4] = (short)f2b_rne(r1b.x); o[5] = (short)f2b_rne(r1b.y);
      o[6] = (short)f2b_rne(r1b.z); o[7] = (short)f2b_rne(r1b.w);
      *(s16x8*)&A[(32 + row) * 72 + c * 8] = o;
    }
    // issue next tile's loads now; they fly through transpose+emit
    if (i < 3) {
      int tix2 = blockIdx.x + 512 * (i + 1);
      int b2 = tix2 >> 8, rem2 = tix2 & 255;
      int s02 = (rem2 >> 3) * 64, d02 = (rem2 & 7) * 64;
      const float* src0 = x + ((size_t)(b2 * S_LEN + s02 + row)) * D_DIM + d02 + c * 8;
      const float* src1 = x + ((size_t)(b2 * S_LEN + s02 + 32 + row)) * D_DIM + d02 + c * 8;
      r0a = *(const float4*)(src0); r0b = *(const float4*)(src0 + 4);
      r1a = *(const float4*)(src1); r1b = *(const float4*)(src1 + 4);
    }
    __syncthreads();

    // transpose A -> T in 4x4 micro-blocks
    {
      int sr = tid >> 4, sc = tid & 15;
      ushort4 a0 = *(const ushort4*)&A[(4 * sr + 0) * 72 + 4 * sc];
      ushort4 a1 = *(const ushort4*)&A[(4 * sr + 1) * 72 + 4 * sc];
      ushort4 a2 = *(const ushort4*)&A[(4 * sr + 2) * 72 + 4 * sc];
      ushort4 a3 = *(const ushort4*)&A[(4 * sr + 3) * 72 + 4 * sc];
      ushort4 t0; t0.x = a0.x; t0.y = a1.x; t0.z = a2.x; t0.w = a3.x;
      ushort4 t1; t1.x = a0.y; t1.y = a1.y; t1.z = a2.y; t1.w = a3.y;
      ushort4 t2; t2.x = a0.z; t2.y = a1.z; t2.z = a2.z; t2.w = a3.z;
      ushort4 t3; t3.x = a0.w; t3.y = a1.w; t3.z = a2.w; t3.w = a3.w;
      *(ushort4*)&T[(4 * sc + 0) * 72 + 4 * sr] = t0;
      *(ushort4*)&T[(4 * sc + 1) * 72 + 4 * sr] = t1;
      *(ushort4*)&T[(4 * sc + 2) * 72 + 4 * sr] = t2;
      *(ushort4*)&T[(4 * sc + 3) * 72 + 4 * sr] = t3;
    }
    __syncthreads();

    // emit fragment blocks (each 64 consecutive threads write 1KB)
    #pragma unroll
    for (int it = 0; it < 2; ++it) {
      int slot = it * 256 + tid;
      int frag = slot >> 6;
      int lane = slot & 63;
      int l15 = lane & 15, quad = lane >> 4;
      int f1 = frag >> 1, f0 = frag & 1;
      {
        s16x8 val = *(const s16x8*)&A[(f1 * 16 + l15) * 72 + f0 * 32 + quad * 8];
        size_t kg = (size_t)(s0 >> 4) + f1, db = (size_t)(d0 >> 5) + f0;
        *(s16x8*)(Kf + (size_t)b * BATCH_ELEMS + (kg * 16 + db) * 512 + lane * 8) = val;
      }
      {
        s16x8 val = *(const s16x8*)&T[(f1 * 16 + l15) * 72 + f0 * 32 + quad * 8];
        size_t dg = (size_t)(d0 >> 4) + f1, kb = (size_t)(s0 >> 5) + f0;
        *(s16x8*)(Vf + (size_t)b * BATCH_ELEMS + (dg * 64 + kb) * 512 + lane * 8) = val;
      }
    }
    __syncthreads();  // A/T safe to overwrite next tile
  }
}

// ---------------------------------------------------------------------------
// Flash attention, phase-offset staged tiles.
// MFMA 16x16x32 layouts: A[m=l15][k=quad*8+j], B[k=quad*8+j][n=l15],
// C/D: col=l15, row=quad*4+reg.
// ---------------------------------------------------------------------------
__global__ __launch_bounds__(128, 2)
void attn_kernel(const unsigned short* __restrict__ Kf,
                 const unsigned short* __restrict__ Vf,
                 float* __restrict__ out) {
  __shared__ unsigned short ldsK[16384];   // 32 frag-blocks (kg2*16+db)*512+lane*8
  __shared__ unsigned short ldsV[16384];   // 32 frag-blocks dg*512+lane*8
  __shared__ unsigned short Pw[2][16 * 40];

  const int bid = blockIdx.x;
  const int bat = bid & 7;
  const int j = bid >> 3;                          // 0..63
  const int t = (j & 1) ? (j >> 1) : (63 - (j >> 1));
  const int q0 = t * 32;
  const int tid = threadIdx.x;
  const int w = tid >> 6;
  const int lane = tid & 63;
  const int l15 = lane & 15, quad = lane >> 4;
  const size_t batOff = (size_t)bat * BATCH_ELEMS;

  // Q fragments (from Kf layout): wave w owns rows q0+16w .. +15, full D.
  s16x8 qf[16];
  {
    const unsigned short* qb = Kf + batOff + ((size_t)(2 * t + w) * 16) * 512 + lane * 8;
    #pragma unroll
    for (int db = 0; db < 16; ++db) qf[db] = *(const s16x8*)(qb + db * 512);
  }

  f32x4 O[32];
  float m[4], l[4];
  #pragma unroll
  for (int n = 0; n < 32; ++n) O[n] = (f32x4){0.f, 0.f, 0.f, 0.f};
  #pragma unroll
  for (int r = 0; r < 4; ++r) { m[r] = -3e38f; l[r] = 0.f; }

  // ---- staging helpers (1KB frag per global_load_lds, width 16) ----
  #define STAGE_K(KT)                                                          \
    {                                                                          \
      const unsigned short* ks =                                               \
          Kf + batOff + (size_t)(KT) * 16384 + (size_t)(w * 16) * 512 + lane * 8; \
      _Pragma("unroll") for (int i_ = 0; i_ < 16; ++i_)                        \
          __builtin_amdgcn_global_load_lds(                                    \
              (const __attribute__((address_space(1))) unsigned int*)(ks + i_ * 512), \
              (__attribute__((address_space(3))) unsigned int*)&ldsK[(w * 16 + i_) * 512], \
              16, 0, 0);                                                       \
    }
  #define STAGE_V(KT)                                                          \
    {                                                                          \
      const unsigned short* vs = Vf + batOff + (size_t)(KT) * 512 + lane * 8;  \
      _Pragma("unroll") for (int i_ = 0; i_ < 16; ++i_) {                      \
        int dg_ = w * 16 + i_;                                                 \
        __builtin_amdgcn_global_load_lds(                                      \
            (const __attribute__((address_space(1))) unsigned int*)(vs + (size_t)dg_ * 32768), \
            (__attribute__((address_space(3))) unsigned int*)&ldsV[dg_ * 512], \
            16, 0, 0);                                                         \
      }                                                                        \
    }

  STAGE_K(0)
  STAGE_V(0)
  __syncthreads();  // tile 0 staged

  for (int kt = 0; kt <= t; ++kt) {
    // ---- QK^T on K[kt]: S[16 rows][32 keys] ----
    f32x4 sacc[2];
    sacc[0] = (f32x4){0.f, 0.f, 0.f, 0.f};
    sacc[1] = (f32x4){0.f, 0.f, 0.f, 0.f};
    #pragma unroll
    for (int db = 0; db < 16; ++db) {
      s16x8 k0 = *(const s16x8*)&ldsK[db * 512 + lane * 8];
      s16x8 k1 = *(const s16x8*)&ldsK[(16 + db) * 512 + lane * 8];
      sacc[0] = __builtin_amdgcn_mfma_f32_16x16x32_bf16(qf[db], k0, sacc[0], 0, 0, 0);
      sacc[1] = __builtin_amdgcn_mfma_f32_16x16x32_bf16(qf[db], k1, sacc[1], 0, 0, 0);
    }
    __syncthreads();      // B1: all K[kt] reads done; V[kt] staging drained
    if (kt < t) STAGE_K(kt + 1)   // flies during softmax + PV

    if (kt == t) {  // causal mask on diagonal tile
      #pragma unroll
      for (int kg2 = 0; kg2 < 2; ++kg2)
        #pragma unroll
        for (int r = 0; r < 4; ++r) {
          int key = kt * 32 + kg2 * 16 + l15;
          int row = q0 + 16 * w + quad * 4 + r;
          if (key > row) sacc[kg2][r] = -3e38f;
        }
    }

    // ---- online softmax (registers + DPP) ----
    float mt[4], alpha[4];
    #pragma unroll
    for (int r = 0; r < 4; ++r)
      mt[r] = red16_max(fmaxf(sacc[0][r], sacc[1][r]));
    bool needAny = (mt[0] > m[0]) | (mt[1] > m[1]) | (mt[2] > m[2]) | (mt[3] > m[3]);
    unsigned long long bal = __ballot(needAny);
    if (bal) {
      #pragma unroll
      for (int r = 0; r < 4; ++r) {
        float mn = fmaxf(m[r], mt[r]);
        alpha[r] = __expf(m[r] - mn);
        m[r] = mn;
      }
    } else {
      #pragma unroll
      for (int r = 0; r < 4; ++r) alpha[r] = 1.0f;
    }
    float p[2][4];
    #pragma unroll
    for (int kg2 = 0; kg2 < 2; ++kg2)
      #pragma unroll
      for (int r = 0; r < 4; ++r) p[kg2][r] = __expf(sacc[kg2][r] - m[r]);
    #pragma unroll
    for (int r = 0; r < 4; ++r)
      l[r] = l[r] * alpha[r] + red16_sum(p[0][r] + p[1][r]);

    // ---- P: C-layout -> A-layout via wave-private LDS ----
    #pragma unroll
    for (int kg2 = 0; kg2 < 2; ++kg2)
      #pragma unroll
      for (int r = 0; r < 4; ++r)
        Pw[w][(quad * 4 + r) * 40 + kg2 * 16 + l15] = f2b_fast(p[kg2][r]);
    s16x8 pa = *(const s16x8*)&Pw[w][l15 * 40 + quad * 8];

    if (bal) {
      #pragma unroll
      for (int n = 0; n < 32; ++n)
        #pragma unroll
        for (int r = 0; r < 4; ++r) O[n][r] *= alpha[r];
    }

    // ---- PV on V[kt]: O[16 rows][512] += P(16x32) * V(32x512) ----
    #pragma unroll
    for (int dg = 0; dg < 32; ++dg) {
      s16x8 vf = *(const s16x8*)&ldsV[dg * 512 + lane * 8];
      O[dg] = __builtin_amdgcn_mfma_f32_16x16x32_bf16(pa, vf, O[dg], 0, 0, 0);
    }
    __syncthreads();      // B2: all V[kt] reads done; K[kt+1] staging drained
    if (kt < t) STAGE_V(kt + 1)   // flies during next QK
  }

  // ---- epilogue ----
  float invl[4];
  #pragma unroll
  for (int r = 0; r < 4; ++r) invl[r] = 1.0f / l[r];
  float* ob = out + ((size_t)(bat * S_LEN + q0 + 16 * w)) * D_DIM;
  #pragma unroll
  for (int dg = 0; dg < 32; ++dg)
    #pragma unroll
    for (int r = 0; r < 4; ++r)
      ob[(size_t)(quad * 4 + r) * D_DIM + dg * 16 + l15] = O[dg][r] * invl[r];
}

extern "C" void kernel_launch(void* const* d_in, const int* in_sizes, int n_in,
                              void* d_out, int out_size, void* d_ws, size_t ws_size,
                              hipStream_t stream) {
  (void)in_sizes; (void)n_in; (void)out_size; (void)ws_size;
  const float* x = (const float*)d_in[0];
  float* out = (float*)d_out;
  unsigned short* Kf = (unsigned short*)d_ws;                         // 16 MiB
  unsigned short* Vf = (unsigned short*)((char*)d_ws + (16u << 20));  // 16 MiB
  pack_kernel<<<512, 256, 0, stream>>>(x, Kf, Vf);
  attn_kernel<<<512, 128, 0, stream>>>(Kf, Vf, out);
}